// Round 3
// baseline (508.670 us; speedup 1.0000x reference)
//
#include <hip/hip_runtime.h>
#include <cstdint>
#include <cstddef>

typedef unsigned short u16;
using f16x8 = __attribute__((ext_vector_type(8))) _Float16;
using f32x4 = __attribute__((ext_vector_type(4))) float;
using u16x4 = __attribute__((ext_vector_type(4))) unsigned short;

__device__ __forceinline__ u16 f2h(float f) {
  union { _Float16 h; u16 u; } c;
  c.h = (_Float16)f;
  return c.u;
}

// async global->LDS, 16B per lane. LDS dest = wave-uniform base + lane*16.
__device__ __forceinline__ void gl_lds16(const void* g, void* lds) {
  __builtin_amdgcn_global_load_lds(
      (const __attribute__((address_space(1))) void*)(uintptr_t)g,
      (__attribute__((address_space(3))) void*)(uint32_t)(uintptr_t)lds,
      16, 0, 0);
}

// ---------------------------------------------------------------------------
// bt-GEMM (known-good from R1): C[m,n] = sum_k A[m,k]*Bt[n,k], fp16 in.
// MODE 0: fp16 out (+bias). 128x128 tile, BK=32, 4 waves, 16x16x32 MFMA.
// ---------------------------------------------------------------------------
template <int MODE>
__global__ __launch_bounds__(256) void gemm_bt(
    const u16* __restrict__ A, const u16* __restrict__ Bt,
    void* __restrict__ Cv, const float* __restrict__ bias,
    int M, int Ncols, int K,
    long long strideA, long long strideB, long long strideC)
{
  __shared__ __align__(16) u16 sA[128 * 32];
  __shared__ __align__(16) u16 sB[128 * 32];

  const int bz = blockIdx.z;
  A  += (size_t)bz * strideA;
  Bt += (size_t)bz * strideB;

  const int m0 = blockIdx.y * 128;
  const int n0 = blockIdx.x * 128;
  const int t    = threadIdx.x;
  const int lane = t & 63;
  const int wave = t >> 6;
  const int wm   = (wave >> 1) * 64;
  const int wn   = (wave & 1) * 64;
  const int lm   = lane & 15;
  const int quad = lane >> 4;

  f32x4 acc[4][4];
#pragma unroll
  for (int i = 0; i < 4; ++i)
#pragma unroll
    for (int j = 0; j < 4; ++j) acc[i][j] = f32x4{0.f, 0.f, 0.f, 0.f};

  const int r0 = t >> 2,        c0 = t & 3;
  const int r1 = (t + 256) >> 2, c1 = t & 3;
  const int ldsb0 = (t & ~63) * 8;
  const int ldsb1 = ((t & ~63) + 256) * 8;

  const int nk = K >> 5;
  for (int kc = 0; kc < nk; ++kc) {
    const int kb = kc * 32;
    gl_lds16(A  + (size_t)(m0 + r0) * K + kb + c0 * 8, sA + ldsb0);
    gl_lds16(A  + (size_t)(m0 + r1) * K + kb + c1 * 8, sA + ldsb1);
    gl_lds16(Bt + (size_t)(n0 + r0) * K + kb + c0 * 8, sB + ldsb0);
    gl_lds16(Bt + (size_t)(n0 + r1) * K + kb + c1 * 8, sB + ldsb1);
    __syncthreads();

    f16x8 af[4], bf[4];
#pragma unroll
    for (int i = 0; i < 4; ++i) {
      af[i] = *(const f16x8*)(sA + (wm + i * 16 + lm) * 32 + quad * 8);
      bf[i] = *(const f16x8*)(sB + (wn + i * 16 + lm) * 32 + quad * 8);
    }
#pragma unroll
    for (int i = 0; i < 4; ++i)
#pragma unroll
      for (int j = 0; j < 4; ++j)
        acc[i][j] = __builtin_amdgcn_mfma_f32_16x16x32_f16(af[i], bf[j], acc[i][j], 0, 0, 0);
    __syncthreads();
  }

  u16* C = (u16*)Cv + (size_t)bz * strideC;
#pragma unroll
  for (int j = 0; j < 4; ++j) {
    const int col = n0 + wn + j * 16 + lm;
    const float bv = bias ? bias[col] : 0.f;
#pragma unroll
    for (int i = 0; i < 4; ++i)
#pragma unroll
      for (int r = 0; r < 4; ++r) {
        const int row = m0 + wm + i * 16 + quad * 4 + r;
        C[(size_t)row * Ncols + col] = f2h(acc[i][j][r] + bv);
      }
  }
}

// ---------------------------------------------------------------------------
// Flash-fused S=ha.h^T -> masked online softmax -> O=P.h -> elu(out/l)
// Block: 512 thr (8 waves), 64 Q-rows, one batch. Grid 256 (batch = blk&7).
// ---------------------------------------------------------------------------
__global__ __launch_bounds__(512, 2) void flash_gat(
    const u16* __restrict__ haP, const u16* __restrict__ hP,
    const u16* __restrict__ hTP, const u16* __restrict__ adjb,
    float* __restrict__ outP)
{
  __shared__ __align__(16) u16 sQ[2 * 64 * 32];    // 2 panels of 32 cols, 8 KB
  __shared__ __align__(16) u16 sK[2 * 128 * 32];   // 16 KB
  __shared__ __align__(16) u16 sP[64 * 136];       // padded stride, 17 KB
  __shared__ float rmA[4][64];
  __shared__ float rsA[4][64];
  __shared__ float m_sh[64], l_sh[64], al_sh[64];

  const int t     = threadIdx.x;
  const int batch = blockIdx.x & 7;                // same batch -> same XCD
  const int q0    = (blockIdx.x >> 3) << 6;
  const int lane  = t & 63;
  const int wave  = t >> 6;
  const int lm    = lane & 15;
  const int quad  = lane >> 4;
  const int wm    = (wave >> 2) * 32;              // QK: 2x4 wave grid over 64x128
  const int wn    = (wave & 3) * 32;
  const int wd    = wave * 64;                     // PV: wave d-slice

  const u16* Q  = haP + ((size_t)batch * 2048 + q0) * 512;
  const u16* K  = hP  + (size_t)batch * 2048 * 512;
  const u16* V  = hTP + (size_t)batch * 512 * 2048;
  const u16* Ar = adjb + ((size_t)batch * 2048 + q0) * 128;
  float* Co = outP + ((size_t)batch * 2048 + q0) * 512;

  if (t < 64) { m_sh[t] = -1e30f; l_sh[t] = 0.f; }

  f32x4 o[4][4];
#pragma unroll
  for (int i = 0; i < 4; ++i)
#pragma unroll
    for (int j = 0; j < 4; ++j) o[i][j] = f32x4{0.f, 0.f, 0.f, 0.f};

  // staging slots: sQ 512 slots (panel t>>8, row (t>>2)&63, chunk t&3)
  const int kkq = t >> 8, rowq = (t >> 2) & 63, chq = t & 3;
  const u16* qsrc = Q + rowq * 512 + kkq * 32 + chq * 8;
  u16* qdst  = sQ + (t & ~63) * 8;
  // sK 1024 slots via 2 instrs: row t>>2 (0..127), chunk t&3; panels at +0 / +32 cols
  const int rowk = t >> 2, chk = t & 3;
  u16* kdst0 = sK + (t & ~63) * 8;
  u16* kdst1 = sK + ((t & ~63) + 512) * 8;

  for (int nt = 0; nt < 16; ++nt) {
    const int n0 = nt * 128;
    f32x4 sacc[2][2];
#pragma unroll
    for (int i = 0; i < 2; ++i)
#pragma unroll
      for (int j = 0; j < 2; ++j) sacc[i][j] = f32x4{0.f, 0.f, 0.f, 0.f};

    const u16* Krow = K + (size_t)(n0 + rowk) * 512 + chk * 8;
    for (int kc = 0; kc < 8; ++kc) {
      const int kb = kc * 64;
      gl_lds16(qsrc + kb, qdst);
      gl_lds16(Krow + kb, kdst0);
      gl_lds16(Krow + kb + 32, kdst1);
      __syncthreads();
#pragma unroll
      for (int kk = 0; kk < 2; ++kk) {
        f16x8 aq[2], bk[2];
#pragma unroll
        for (int i = 0; i < 2; ++i)
          aq[i] = *(const f16x8*)(sQ + kk * 2048 + (wm + i * 16 + lm) * 32 + quad * 8);
#pragma unroll
        for (int j = 0; j < 2; ++j)
          bk[j] = *(const f16x8*)(sK + kk * 4096 + (wn + j * 16 + lm) * 32 + quad * 8);
#pragma unroll
        for (int i = 0; i < 2; ++i)
#pragma unroll
          for (int j = 0; j < 2; ++j)
            sacc[i][j] = __builtin_amdgcn_mfma_f32_16x16x32_f16(aq[i], bk[j], sacc[i][j], 0, 0, 0);
      }
      __syncthreads();
    }

    // ---- mask + per-wave row max (C-layout: row=quad*4+r, col=lane&15) ----
#pragma unroll
    for (int i = 0; i < 2; ++i)
#pragma unroll
      for (int r = 0; r < 4; ++r) {
        const int R = wm + i * 16 + quad * 4 + r;
        const u16* ab = Ar + R * 128 + nt * 8 + (wn >> 4);
        const unsigned w0 = ab[0], w1 = ab[1];
        float s0 = sacc[i][0][r], s1 = sacc[i][1][r];
        s0 = ((w0 >> lm) & 1u) ? s0 : -1e30f;
        s1 = ((w1 >> lm) & 1u) ? s1 : -1e30f;
        sacc[i][0][r] = s0; sacc[i][1][r] = s1;
        float m = fmaxf(s0, s1);
        m = fmaxf(m, __shfl_xor(m, 1));
        m = fmaxf(m, __shfl_xor(m, 2));
        m = fmaxf(m, __shfl_xor(m, 4));
        m = fmaxf(m, __shfl_xor(m, 8));
        if (lm == 0) rmA[wave & 3][R] = m;
      }
    __syncthreads();  // B1

    // ---- exp + P~ to LDS + per-wave row sums ----
#pragma unroll
    for (int i = 0; i < 2; ++i)
#pragma unroll
      for (int r = 0; r < 4; ++r) {
        const int R = wm + i * 16 + quad * 4 + r;
        const float cm = fmaxf(fmaxf(rmA[0][R], rmA[1][R]), fmaxf(rmA[2][R], rmA[3][R]));
        const float nm = fmaxf(m_sh[R], cm);
        const float p0 = __expf(sacc[i][0][r] - nm);
        const float p1 = __expf(sacc[i][1][r] - nm);
        sP[R * 136 + wn + lm]      = f2h(p0);
        sP[R * 136 + wn + 16 + lm] = f2h(p1);
        float rr = p0 + p1;
        rr += __shfl_xor(rr, 1);
        rr += __shfl_xor(rr, 2);
        rr += __shfl_xor(rr, 4);
        rr += __shfl_xor(rr, 8);
        if (lm == 0) rsA[wave & 3][R] = rr;
      }
    __syncthreads();  // B2

    // ---- state update (one thread per row) ----
    if (t < 64) {
      const float cm = fmaxf(fmaxf(rmA[0][t], rmA[1][t]), fmaxf(rmA[2][t], rmA[3][t]));
      const float mo = m_sh[t];
      const float nm = fmaxf(mo, cm);
      const float a  = __expf(mo - nm);
      l_sh[t]  = a * l_sh[t] + rsA[0][t] + rsA[1][t] + rsA[2][t] + rsA[3][t];
      m_sh[t]  = nm;
      al_sh[t] = a;
    }
    __syncthreads();  // B3

    // ---- O rescale + PV (V-frags direct from global hT; no barriers) ----
#pragma unroll
    for (int i = 0; i < 4; ++i)
#pragma unroll
      for (int r = 0; r < 4; ++r) {
        const float a = al_sh[i * 16 + quad * 4 + r];
#pragma unroll
        for (int j = 0; j < 4; ++j) o[i][j][r] *= a;
      }
#pragma unroll
    for (int kb = 0; kb < 4; ++kb) {
      f16x8 ap[4], bv[4];
#pragma unroll
      for (int i = 0; i < 4; ++i)
        ap[i] = *(const f16x8*)(sP + (i * 16 + lm) * 136 + kb * 32 + quad * 8);
#pragma unroll
      for (int j = 0; j < 4; ++j)
        bv[j] = *(const f16x8*)(V + (size_t)(wd + j * 16 + lm) * 2048 + n0 + kb * 32 + quad * 8);
#pragma unroll
      for (int i = 0; i < 4; ++i)
#pragma unroll
        for (int j = 0; j < 4; ++j)
          o[i][j] = __builtin_amdgcn_mfma_f32_16x16x32_f16(ap[i], bv[j], o[i][j], 0, 0, 0);
    }
  }

  // ---- epilogue: out = elu(O / l) ----
#pragma unroll
  for (int i = 0; i < 4; ++i)
#pragma unroll
    for (int r = 0; r < 4; ++r) {
      const int R = i * 16 + quad * 4 + r;
      const float inv = 1.f / l_sh[R];
#pragma unroll
      for (int j = 0; j < 4; ++j) {
        float v = o[i][j][r] * inv;
        v = v > 0.f ? v : expm1f(v);
        Co[(size_t)R * 512 + wd + j * 16 + lm] = v;
      }
    }
}

// ---------------------------------------------------------------------------
// adjacency -> bitmask: word i packs adj[i*16 .. i*16+16) (bit e = col e)
// ---------------------------------------------------------------------------
__global__ __launch_bounds__(256) void adj_pack(
    const int* __restrict__ adj, u16* __restrict__ outw, int nwords)
{
  const int i = blockIdx.x * 256 + threadIdx.x;
  if (i >= nwords) return;
  const int4* p = (const int4*)(adj + (size_t)i * 16);
  unsigned w = 0;
#pragma unroll
  for (int k = 0; k < 4; ++k) {
    int4 v = p[k];
    w |= (unsigned)(v.x != 0) << (k * 4 + 0);
    w |= (unsigned)(v.y != 0) << (k * 4 + 1);
    w |= (unsigned)(v.z != 0) << (k * 4 + 2);
    w |= (unsigned)(v.w != 0) << (k * 4 + 3);
  }
  outw[i] = (u16)w;
}

// ---------------------------------------------------------------------------
__global__ __launch_bounds__(256) void transpose_u16(
    const u16* __restrict__ in, u16* __restrict__ outp, int R, int C)
{
  __shared__ u16 tile[64][65];
  const size_t base = (size_t)blockIdx.z * R * C;
  const int r0 = blockIdx.y * 64, c0 = blockIdx.x * 64;
  const int t = threadIdx.x;
  const int c = t & 63, rr = t >> 6;
#pragma unroll
  for (int i = 0; i < 16; ++i) {
    const int r = rr + i * 4;
    tile[r][c] = in[base + (size_t)(r0 + r) * C + c0 + c];
  }
  __syncthreads();
  const int rp = t & 63, cc = t >> 6;
#pragma unroll
  for (int i = 0; i < 16; ++i) {
    const int cq = cc + i * 4;
    outp[base + (size_t)(c0 + cq) * R + r0 + rp] = tile[rp][cq];
  }
}

__global__ __launch_bounds__(256) void cvt_f32_f16(
    const float* __restrict__ in, u16* __restrict__ outp, int n4)
{
  const int i = blockIdx.x * 256 + threadIdx.x;
  if (i >= n4) return;
  float4 v = ((const float4*)in)[i];
  u16x4 o; o[0] = f2h(v.x); o[1] = f2h(v.y); o[2] = f2h(v.z); o[3] = f2h(v.w);
  ((u16x4*)outp)[i] = o;
}

__global__ __launch_bounds__(256) void transpose_cvt(
    const float* __restrict__ in, u16* __restrict__ outp, int R, int C)
{
  const int idx = blockIdx.x * 256 + threadIdx.x;
  const int i = idx / C, j = idx % C;
  outp[(size_t)j * R + i] = f2h(in[idx]);
}

// ---------------------------------------------------------------------------
extern "C" void kernel_launch(void* const* d_in, const int* in_sizes, int n_in,
                              void* d_out, int out_size, void* d_ws, size_t ws_size,
                              hipStream_t stream) {
  (void)in_sizes; (void)n_in; (void)out_size;
  const float* x    = (const float*)d_in[0];
  const int*   adj  = (const int*)d_in[1];
  const float* W    = (const float*)d_in[2];
  const float* bvec = (const float*)d_in[3];
  const float* attn = (const float*)d_in[4];
  float* out = (float*)d_out;

  constexpr int B = 8, N = 2048, D = 512;
  constexpr size_t MN = (size_t)B * N;  // 16384

  char* ws = (char*)d_ws;
  size_t off = 0;
  auto take = [&](size_t bytes) -> char* {
    char* p = ws + off;
    off += (bytes + 255) & ~(size_t)255;
    return p;
  };
  u16* xh   = (u16*)take(MN * D * 2);
  u16* Wh   = (u16*)take((size_t)D * D * 2);
  u16* attT = (u16*)take((size_t)D * D * 2);
  u16* h    = (u16*)take(MN * D * 2);
  u16* hT   = (u16*)take(MN * D * 2);
  u16* ha   = (u16*)take(MN * D * 2);
  u16* adjb = (u16*)take((size_t)B * N * (N / 16) * 2);  // 4 MB
  if (off > ws_size) return;

  // converts + adjacency pack
  cvt_f32_f16<<<dim3((unsigned)(MN * D / 4 / 256)), 256, 0, stream>>>(x, xh, (int)(MN * D / 4));
  cvt_f32_f16<<<dim3(D * D / 4 / 256), 256, 0, stream>>>(W, Wh, D * D / 4);
  transpose_cvt<<<dim3(D * D / 256), 256, 0, stream>>>(attn, attT, D, D);
  const int nwords = (int)(MN * (N / 16));  // 2,097,152
  adj_pack<<<dim3(nwords / 256), 256, 0, stream>>>(adj, adjb, nwords);

  // K1: h = xh . Wh^T + bias
  gemm_bt<0><<<dim3(D / 128, MN / 128, 1), 256, 0, stream>>>(
      xh, Wh, h, bvec, (int)MN, D, D, 0, 0, 0);
  // hT per batch
  transpose_u16<<<dim3(D / 64, N / 64, B), 256, 0, stream>>>(h, hT, N, D);
  // K2: ha = h . attT^T
  gemm_bt<0><<<dim3(D / 128, MN / 128, 1), 256, 0, stream>>>(
      h, attT, ha, nullptr, (int)MN, D, D, 0, 0, 0);

  // fused S -> masked softmax -> PV -> elu
  flash_gat<<<dim3(256), 512, 0, stream>>>(ha, h, hT, adjb, out);
}

// Round 4
// 496.052 us; speedup vs baseline: 1.0254x; 1.0254x over previous
//
#include <hip/hip_runtime.h>
#include <cstdint>
#include <cstddef>

typedef unsigned short u16;
using f16x8 = __attribute__((ext_vector_type(8))) _Float16;
using f32x4 = __attribute__((ext_vector_type(4))) float;
using u16x4 = __attribute__((ext_vector_type(4))) unsigned short;

__device__ __forceinline__ u16 f2h(float f) {
  union { _Float16 h; u16 u; } c;
  c.h = (_Float16)f;
  return c.u;
}

// async global->LDS, 16B per lane. LDS dest = wave-uniform base + lane*16.
__device__ __forceinline__ void gl_lds16(const void* g, void* lds) {
  __builtin_amdgcn_global_load_lds(
      (const __attribute__((address_space(1))) void*)(uintptr_t)g,
      (__attribute__((address_space(3))) void*)(uint32_t)(uintptr_t)lds,
      16, 0, 0);
}

// ---------------------------------------------------------------------------
// bt-GEMM: C[m,n] = sum_k A[m,k]*Bt[n,k], fp16. 128x128 tile, BK=32, 4 waves.
// MODE 0: fp16 out (+bias if non-null). MODE 3: fp16 out + bias + transposed
// copy to hTp laid out [batch(row>>11)][col][row&2047].
// ---------------------------------------------------------------------------
template <int MODE>
__global__ __launch_bounds__(256) void gemm_bt(
    const u16* __restrict__ A, const u16* __restrict__ Bt,
    u16* __restrict__ C, const float* __restrict__ bias,
    u16* __restrict__ hTp, int Ncols, int K)
{
  __shared__ __align__(16) u16 sA[128 * 32];
  __shared__ __align__(16) u16 sB[128 * 32];

  const int m0 = blockIdx.y * 128;
  const int n0 = blockIdx.x * 128;
  const int t    = threadIdx.x;
  const int lane = t & 63;
  const int wave = t >> 6;
  const int wm   = (wave >> 1) * 64;
  const int wn   = (wave & 1) * 64;
  const int lm   = lane & 15;
  const int quad = lane >> 4;

  f32x4 acc[4][4];
#pragma unroll
  for (int i = 0; i < 4; ++i)
#pragma unroll
    for (int j = 0; j < 4; ++j) acc[i][j] = f32x4{0.f, 0.f, 0.f, 0.f};

  const int r0 = t >> 2,         c0 = t & 3;
  const int r1 = (t + 256) >> 2;
  const int ldsb0 = (t & ~63) * 8;
  const int ldsb1 = ((t & ~63) + 256) * 8;

  const int nk = K >> 5;
  for (int kc = 0; kc < nk; ++kc) {
    const int kb = kc * 32;
    gl_lds16(A  + (size_t)(m0 + r0) * K + kb + c0 * 8, sA + ldsb0);
    gl_lds16(A  + (size_t)(m0 + r1) * K + kb + c0 * 8, sA + ldsb1);
    gl_lds16(Bt + (size_t)(n0 + r0) * K + kb + c0 * 8, sB + ldsb0);
    gl_lds16(Bt + (size_t)(n0 + r1) * K + kb + c0 * 8, sB + ldsb1);
    __syncthreads();

    f16x8 af[4], bf[4];
#pragma unroll
    for (int i = 0; i < 4; ++i) {
      af[i] = *(const f16x8*)(sA + (wm + i * 16 + lm) * 32 + quad * 8);
      bf[i] = *(const f16x8*)(sB + (wn + i * 16 + lm) * 32 + quad * 8);
    }
#pragma unroll
    for (int i = 0; i < 4; ++i)
#pragma unroll
      for (int j = 0; j < 4; ++j)
        acc[i][j] = __builtin_amdgcn_mfma_f32_16x16x32_f16(af[i], bf[j], acc[i][j], 0, 0, 0);
    __syncthreads();
  }

  // C/D layout: col=lane&15, row=quad*4+reg  [m89-verified]
#pragma unroll
  for (int j = 0; j < 4; ++j) {
    const int col = n0 + wn + j * 16 + lm;
    const float bv = bias ? bias[col] : 0.f;
#pragma unroll
    for (int i = 0; i < 4; ++i) {
      const int row0 = m0 + wm + i * 16 + quad * 4;
      u16x4 tp;
#pragma unroll
      for (int r = 0; r < 4; ++r) {
        const u16 hv = f2h(acc[i][j][r] + bv);
        C[(size_t)(row0 + r) * Ncols + col] = hv;
        tp[r] = hv;
      }
      if (MODE == 3) {
        const int b = row0 >> 11, n = row0 & 2047;
        *(u16x4*)(hTp + ((size_t)b * 512 + col) * 2048 + n) = tp;
      }
    }
  }
}

// ---------------------------------------------------------------------------
// Flash-fused S=ha.h^T -> masked online softmax -> O=P.h -> elu(O/l)
// Block: 256 thr (4 waves), 32 Q-rows, one batch. Grid 512 (= 2 blocks/CU).
// QK: waves 2x2 over 32x128 (each 16x64). PV: each wave a 128-wide d-slice.
// ---------------------------------------------------------------------------
__global__ __launch_bounds__(256, 2) void flash_gat(
    const u16* __restrict__ haP, const u16* __restrict__ hP,
    const u16* __restrict__ hTP, const u16* __restrict__ adjb,
    float* __restrict__ outP)
{
  __shared__ __align__(16) u16 sQ[4 * 32 * 32];    // 8 KB, 4 k-panels
  __shared__ __align__(16) u16 sK[4 * 128 * 32];   // 32 KB, 4 k-panels
  __shared__ __align__(16) u16 sP[32 * 136];       // 8.7 KB, padded stride
  __shared__ float rmA[2][32], rsA[2][32];
  __shared__ float m_sh[32], l_sh[32], al_sh[32];

  const int t     = threadIdx.x;
  const int batch = blockIdx.x & 7;                // batch -> XCD affinity
  const int q0    = (blockIdx.x >> 3) << 5;
  const int lane  = t & 63;
  const int wave  = t >> 6;
  const int lm    = lane & 15;
  const int quad  = lane >> 4;
  const int wqm   = (wave >> 1) * 16;              // QK row offset
  const int wqn   = (wave & 1) * 64;               // QK col offset
  const int wd    = wave * 128;                    // PV d-slice

  const u16* Q  = haP + ((size_t)batch * 2048 + q0) * 512;
  const u16* K  = hP  + (size_t)batch * 2048 * 512;
  const u16* V  = hTP + (size_t)batch * 512 * 2048;
  const u16* Ar = adjb + ((size_t)batch * 2048 + q0) * 128;
  float* Co = outP + ((size_t)batch * 2048 + q0) * 512;

  if (t < 32) { m_sh[t] = -1e30f; l_sh[t] = 0.f; }

  f32x4 o[2][8];
#pragma unroll
  for (int i = 0; i < 2; ++i)
#pragma unroll
    for (int j = 0; j < 8; ++j) o[i][j] = f32x4{0.f, 0.f, 0.f, 0.f};

  for (int nt = 0; nt < 16; ++nt) {
    const int n0 = nt * 128;
    f32x4 sacc[4];
#pragma unroll
    for (int j = 0; j < 4; ++j) sacc[j] = f32x4{0.f, 0.f, 0.f, 0.f};

    for (int kc = 0; kc < 4; ++kc) {
      // stage K-tile panel group: 128 rows x 128 k (4 panels of 32 k), 32 KB
#pragma unroll
      for (int c = 0; c < 8; ++c) {
        const int s = c * 256 + t;
        const int q = s & 3, r = (s >> 2) & 127, pk = s >> 9;
        gl_lds16(K + (size_t)(n0 + r) * 512 + kc * 128 + pk * 32 + q * 8,
                 sK + (size_t)(c * 256 + (t & ~63)) * 8);
      }
      // stage Q panel group: 32 rows x 128 k, 8 KB
#pragma unroll
      for (int c = 0; c < 2; ++c) {
        const int s = c * 256 + t;
        const int q = s & 3, r = (s >> 2) & 31, p = s >> 7;
        gl_lds16(Q + (size_t)r * 512 + kc * 128 + p * 32 + q * 8,
                 sQ + (size_t)(c * 256 + (t & ~63)) * 8);
      }
      __syncthreads();

#pragma unroll
      for (int kk = 0; kk < 4; ++kk) {
        const f16x8 aq = *(const f16x8*)(sQ + kk * 1024 + (wqm + lm) * 32 + quad * 8);
        f16x8 bk[4];
#pragma unroll
        for (int j = 0; j < 4; ++j)
          bk[j] = *(const f16x8*)(sK + kk * 4096 + (wqn + j * 16 + lm) * 32 + quad * 8);
#pragma unroll
        for (int j = 0; j < 4; ++j)
          sacc[j] = __builtin_amdgcn_mfma_f32_16x16x32_f16(aq, bk[j], sacc[j], 0, 0, 0);
      }
      __syncthreads();
    }

    // ---- mask + per-wave row max (C-layout: row=quad*4+r, col=lane&15) ----
#pragma unroll
    for (int r = 0; r < 4; ++r) {
      const int R = wqm + quad * 4 + r;
      const u16x4 aw = *(const u16x4*)(Ar + (size_t)R * 128 + nt * 8 + (wqn >> 4));
      float mx = -1e30f;
#pragma unroll
      for (int j = 0; j < 4; ++j) {
        float s = sacc[j][r];
        s = ((aw[j] >> lm) & 1u) ? s : -1e30f;
        sacc[j][r] = s;
        mx = fmaxf(mx, s);
      }
      mx = fmaxf(mx, __shfl_xor(mx, 1));
      mx = fmaxf(mx, __shfl_xor(mx, 2));
      mx = fmaxf(mx, __shfl_xor(mx, 4));
      mx = fmaxf(mx, __shfl_xor(mx, 8));
      if (lm == 0) rmA[wave & 1][R] = mx;
    }
    __syncthreads();  // B1

    // ---- exp + P~ to LDS + per-wave row sums ----
#pragma unroll
    for (int r = 0; r < 4; ++r) {
      const int R = wqm + quad * 4 + r;
      const float cm = fmaxf(rmA[0][R], rmA[1][R]);
      const float nm = fmaxf(m_sh[R], cm);
      float rs = 0.f;
#pragma unroll
      for (int j = 0; j < 4; ++j) {
        const float p = __expf(sacc[j][r] - nm);
        rs += p;
        sP[R * 136 + wqn + j * 16 + lm] = f2h(p);
      }
      rs += __shfl_xor(rs, 1);
      rs += __shfl_xor(rs, 2);
      rs += __shfl_xor(rs, 4);
      rs += __shfl_xor(rs, 8);
      if (lm == 0) rsA[wave & 1][R] = rs;
    }
    __syncthreads();  // B2

    // ---- state update ----
    if (t < 32) {
      const float cm = fmaxf(rmA[0][t], rmA[1][t]);
      const float mo = m_sh[t];
      const float nm = fmaxf(mo, cm);
      const float a  = __expf(mo - nm);
      l_sh[t]  = a * l_sh[t] + rsA[0][t] + rsA[1][t];
      m_sh[t]  = nm;
      al_sh[t] = a;
    }
    __syncthreads();  // B3

    // ---- O rescale + PV (V-frags direct from global hT; line-covered) ----
#pragma unroll
    for (int i = 0; i < 2; ++i)
#pragma unroll
      for (int r = 0; r < 4; ++r) {
        const float a = al_sh[i * 16 + quad * 4 + r];
#pragma unroll
        for (int j = 0; j < 8; ++j) o[i][j][r] *= a;
      }
#pragma unroll
    for (int kb = 0; kb < 4; ++kb) {
      f16x8 ap[2], bv[8];
#pragma unroll
      for (int i = 0; i < 2; ++i)
        ap[i] = *(const f16x8*)(sP + (i * 16 + lm) * 136 + kb * 32 + quad * 8);
#pragma unroll
      for (int j = 0; j < 8; ++j)
        bv[j] = *(const f16x8*)(V + (size_t)(wd + j * 16 + lm) * 2048 + n0 + kb * 32 + quad * 8);
#pragma unroll
      for (int i = 0; i < 2; ++i)
#pragma unroll
        for (int j = 0; j < 8; ++j)
          o[i][j] = __builtin_amdgcn_mfma_f32_16x16x32_f16(ap[i], bv[j], o[i][j], 0, 0, 0);
    }
  }

  // ---- epilogue: out = elu(O / l) ----
#pragma unroll
  for (int i = 0; i < 2; ++i)
#pragma unroll
    for (int r = 0; r < 4; ++r) {
      const int R = i * 16 + quad * 4 + r;
      const float inv = 1.f / l_sh[R];
#pragma unroll
      for (int j = 0; j < 8; ++j) {
        float v = o[i][j][r] * inv;
        v = v > 0.f ? v : expm1f(v);
        Co[(size_t)R * 512 + wd + j * 16 + lm] = v;
      }
    }
}

// ---------------------------------------------------------------------------
// adjacency -> bitmask: word i packs adj[i*16 .. i*16+16) (bit e = col e)
// ---------------------------------------------------------------------------
__global__ __launch_bounds__(256) void adj_pack(
    const int* __restrict__ adj, u16* __restrict__ outw, int nwords)
{
  const int i = blockIdx.x * 256 + threadIdx.x;
  if (i >= nwords) return;
  const int4* p = (const int4*)(adj + (size_t)i * 16);
  unsigned w = 0;
#pragma unroll
  for (int k = 0; k < 4; ++k) {
    int4 v = p[k];
    w |= (unsigned)(v.x != 0) << (k * 4 + 0);
    w |= (unsigned)(v.y != 0) << (k * 4 + 1);
    w |= (unsigned)(v.z != 0) << (k * 4 + 2);
    w |= (unsigned)(v.w != 0) << (k * 4 + 3);
  }
  outw[i] = (u16)w;
}

__global__ __launch_bounds__(256) void cvt_f32_f16(
    const float* __restrict__ in, u16* __restrict__ outp, int n4)
{
  const int i = blockIdx.x * 256 + threadIdx.x;
  if (i >= n4) return;
  float4 v = ((const float4*)in)[i];
  u16x4 o; o[0] = f2h(v.x); o[1] = f2h(v.y); o[2] = f2h(v.z); o[3] = f2h(v.w);
  ((u16x4*)outp)[i] = o;
}

__global__ __launch_bounds__(256) void transpose_cvt(
    const float* __restrict__ in, u16* __restrict__ outp, int R, int C)
{
  const int idx = blockIdx.x * 256 + threadIdx.x;
  const int i = idx / C, j = idx % C;
  outp[(size_t)j * R + i] = f2h(in[idx]);
}

// ---------------------------------------------------------------------------
extern "C" void kernel_launch(void* const* d_in, const int* in_sizes, int n_in,
                              void* d_out, int out_size, void* d_ws, size_t ws_size,
                              hipStream_t stream) {
  (void)in_sizes; (void)n_in; (void)out_size;
  const float* x    = (const float*)d_in[0];
  const int*   adj  = (const int*)d_in[1];
  const float* W    = (const float*)d_in[2];
  const float* bvec = (const float*)d_in[3];
  const float* attn = (const float*)d_in[4];
  float* out = (float*)d_out;

  constexpr int B = 8, N = 2048, D = 512;
  constexpr size_t MN = (size_t)B * N;  // 16384

  char* ws = (char*)d_ws;
  size_t off = 0;
  auto take = [&](size_t bytes) -> char* {
    char* p = ws + off;
    off += (bytes + 255) & ~(size_t)255;
    return p;
  };
  u16* xh   = (u16*)take(MN * D * 2);
  u16* Wh   = (u16*)take((size_t)D * D * 2);
  u16* attT = (u16*)take((size_t)D * D * 2);
  u16* h    = (u16*)take(MN * D * 2);
  u16* hT   = (u16*)take(MN * D * 2);
  u16* ha   = (u16*)take(MN * D * 2);
  u16* adjb = (u16*)take((size_t)B * N * (N / 16) * 2);  // 4 MB
  if (off > ws_size) return;

  // converts + adjacency pack
  cvt_f32_f16<<<dim3((unsigned)(MN * D / 4 / 256)), 256, 0, stream>>>(x, xh, (int)(MN * D / 4));
  cvt_f32_f16<<<dim3(D * D / 4 / 256), 256, 0, stream>>>(W, Wh, D * D / 4);
  transpose_cvt<<<dim3(D * D / 256), 256, 0, stream>>>(attn, attT, D, D);
  const int nwords = (int)(MN * (N / 16));
  adj_pack<<<dim3(nwords / 256), 256, 0, stream>>>(adj, adjb, nwords);

  // K1: h = xh . Wh^T + bias (also writes hT)
  gemm_bt<3><<<dim3(D / 128, MN / 128), 256, 0, stream>>>(
      xh, Wh, h, bvec, hT, D, D);
  // K2: ha = h . attT^T
  gemm_bt<0><<<dim3(D / 128, MN / 128), 256, 0, stream>>>(
      h, attT, ha, nullptr, nullptr, D, D);

  // fused S -> masked softmax -> PV -> elu
  flash_gat<<<dim3(512), 256, 0, stream>>>(ha, h, hT, adjb, out);
}

// Round 5
// 488.809 us; speedup vs baseline: 1.0406x; 1.0148x over previous
//
#include <hip/hip_runtime.h>
#include <cstdint>
#include <cstddef>

typedef unsigned short u16;
using f16x8 = __attribute__((ext_vector_type(8))) _Float16;
using f32x4 = __attribute__((ext_vector_type(4))) float;
using u16x4 = __attribute__((ext_vector_type(4))) unsigned short;

__device__ __forceinline__ u16 f2h(float f) {
  union { _Float16 h; u16 u; } c;
  c.h = (_Float16)f;
  return c.u;
}

// async global->LDS, 16B per lane. LDS dest = wave-uniform base + lane*16.
__device__ __forceinline__ void gl_lds16(const void* g, void* lds) {
  __builtin_amdgcn_global_load_lds(
      (const __attribute__((address_space(1))) void*)(uintptr_t)g,
      (__attribute__((address_space(3))) void*)(uint32_t)(uintptr_t)lds,
      16, 0, 0);
}

// LDS chunk swizzle: slot chunk q of row r holds global chunk q ^ ((r>>1)&3).
// Frag read of chunk `quad` from row (base16 + lm) -> LDS chunk quad ^ ((lm>>1)&3),
// giving 2-way (free) bank access instead of 8-way on 64B-stride rows.

// ---------------------------------------------------------------------------
// bt-GEMM: C[m,n] = sum_k A[m,k]*Bt[n,k], fp16. 128x128 tile, BK=32, 4 waves.
// MODE 0: fp16 out (+bias if non-null). MODE 3: fp16 out + bias + transposed
// copy to hTp laid out [batch(row>>11)][col][row&2047].
// ---------------------------------------------------------------------------
template <int MODE>
__global__ __launch_bounds__(256) void gemm_bt(
    const u16* __restrict__ A, const u16* __restrict__ Bt,
    u16* __restrict__ C, const float* __restrict__ bias,
    u16* __restrict__ hTp, int Ncols, int K)
{
  __shared__ __align__(16) u16 sA[128 * 32];
  __shared__ __align__(16) u16 sB[128 * 32];

  const int m0 = blockIdx.y * 128;
  const int n0 = blockIdx.x * 128;
  const int t    = threadIdx.x;
  const int lane = t & 63;
  const int wave = t >> 6;
  const int wm   = (wave >> 1) * 64;
  const int wn   = (wave & 1) * 64;
  const int lm   = lane & 15;
  const int quad = lane >> 4;
  const int sw   = (quad ^ ((lm >> 1) & 3)) * 8;   // swizzled chunk offset (u16)

  f32x4 acc[4][4];
#pragma unroll
  for (int i = 0; i < 4; ++i)
#pragma unroll
    for (int j = 0; j < 4; ++j) acc[i][j] = f32x4{0.f, 0.f, 0.f, 0.f};

  const int r0 = t >> 2,         c0 = t & 3;
  const int r1 = (t + 256) >> 2;
  const int g0 = c0 ^ ((r0 >> 1) & 3);             // swizzled global chunk
  const int g1 = c0 ^ ((r1 >> 1) & 3);
  const int ldsb0 = (t & ~63) * 8;
  const int ldsb1 = ((t & ~63) + 256) * 8;

  const int nk = K >> 5;
  for (int kc = 0; kc < nk; ++kc) {
    const int kb = kc * 32;
    gl_lds16(A  + (size_t)(m0 + r0) * K + kb + g0 * 8, sA + ldsb0);
    gl_lds16(A  + (size_t)(m0 + r1) * K + kb + g1 * 8, sA + ldsb1);
    gl_lds16(Bt + (size_t)(n0 + r0) * K + kb + g0 * 8, sB + ldsb0);
    gl_lds16(Bt + (size_t)(n0 + r1) * K + kb + g1 * 8, sB + ldsb1);
    __syncthreads();

    f16x8 af[4], bf[4];
#pragma unroll
    for (int i = 0; i < 4; ++i) {
      af[i] = *(const f16x8*)(sA + (wm + i * 16 + lm) * 32 + sw);
      bf[i] = *(const f16x8*)(sB + (wn + i * 16 + lm) * 32 + sw);
    }
#pragma unroll
    for (int i = 0; i < 4; ++i)
#pragma unroll
      for (int j = 0; j < 4; ++j)
        acc[i][j] = __builtin_amdgcn_mfma_f32_16x16x32_f16(af[i], bf[j], acc[i][j], 0, 0, 0);
    __syncthreads();
  }

  // C/D layout: col=lane&15, row=quad*4+reg  [m89-verified]
#pragma unroll
  for (int j = 0; j < 4; ++j) {
    const int col = n0 + wn + j * 16 + lm;
    const float bv = bias ? bias[col] : 0.f;
#pragma unroll
    for (int i = 0; i < 4; ++i) {
      const int row0 = m0 + wm + i * 16 + quad * 4;
      u16x4 tp;
#pragma unroll
      for (int r = 0; r < 4; ++r) {
        const u16 hv = f2h(acc[i][j][r] + bv);
        C[(size_t)(row0 + r) * Ncols + col] = hv;
        tp[r] = hv;
      }
      if (MODE == 3) {
        const int b = row0 >> 11, n = row0 & 2047;
        *(u16x4*)(hTp + ((size_t)b * 512 + col) * 2048 + n) = tp;
      }
    }
  }
}

// ---------------------------------------------------------------------------
// Flash-fused S=ha.h^T -> masked online softmax -> O=P.h -> elu(O/l)
// Block: 256 thr (4 waves), 32 Q-rows, one batch. Grid 512 (= 2 blocks/CU).
// QK: waves 2x2 over 32x128 (each 16x64). PV: each wave a 128-wide d-slice.
// ---------------------------------------------------------------------------
__global__ __launch_bounds__(256, 2) void flash_gat(
    const u16* __restrict__ haP, const u16* __restrict__ hP,
    const u16* __restrict__ hTP, const u16* __restrict__ adjb,
    float* __restrict__ outP)
{
  __shared__ __align__(16) u16 sQ[4 * 32 * 32];    // 8 KB, 4 k-panels
  __shared__ __align__(16) u16 sK[4 * 128 * 32];   // 32 KB, 4 k-panels
  __shared__ __align__(16) u16 sP[32 * 136];       // 8.7 KB, padded stride
  __shared__ float rmA[2][32], rsA[2][32];
  __shared__ float m_sh[32], l_sh[32], al_sh[32];

  const int t     = threadIdx.x;
  const int batch = blockIdx.x & 7;                // batch -> XCD affinity
  const int q0    = (blockIdx.x >> 3) << 5;
  const int lane  = t & 63;
  const int wave  = t >> 6;
  const int lm    = lane & 15;
  const int quad  = lane >> 4;
  const int sw    = (quad ^ ((lm >> 1) & 3)) * 8;  // swizzled chunk offset (u16)
  const int wqm   = (wave >> 1) * 16;              // QK row offset
  const int wqn   = (wave & 1) * 64;               // QK col offset
  const int wd    = wave * 128;                    // PV d-slice

  const u16* Q  = haP + ((size_t)batch * 2048 + q0) * 512;
  const u16* K  = hP  + (size_t)batch * 2048 * 512;
  const u16* V  = hTP + (size_t)batch * 512 * 2048;
  const u16* Ar = adjb + ((size_t)batch * 2048 + q0) * 128;
  float* Co = outP + ((size_t)batch * 2048 + q0) * 512;

  if (t < 32) { m_sh[t] = -1e30f; l_sh[t] = 0.f; }

  f32x4 o[2][8];
#pragma unroll
  for (int i = 0; i < 2; ++i)
#pragma unroll
    for (int j = 0; j < 8; ++j) o[i][j] = f32x4{0.f, 0.f, 0.f, 0.f};

  for (int nt = 0; nt < 16; ++nt) {
    const int n0 = nt * 128;
    f32x4 sacc[4];
#pragma unroll
    for (int j = 0; j < 4; ++j) sacc[j] = f32x4{0.f, 0.f, 0.f, 0.f};

    for (int kc = 0; kc < 4; ++kc) {
      // stage K-tile panel group: 128 rows x 128 k (4 panels of 32 k), 32 KB
#pragma unroll
      for (int c = 0; c < 8; ++c) {
        const int s = c * 256 + t;
        const int q = s & 3, r = (s >> 2) & 127, pk = s >> 9;
        const int g = q ^ ((r >> 1) & 3);
        gl_lds16(K + (size_t)(n0 + r) * 512 + kc * 128 + pk * 32 + g * 8,
                 sK + (size_t)(c * 256 + (t & ~63)) * 8);
      }
      // stage Q panel group: 32 rows x 128 k, 8 KB
#pragma unroll
      for (int c = 0; c < 2; ++c) {
        const int s = c * 256 + t;
        const int q = s & 3, r = (s >> 2) & 31, p = s >> 7;
        const int g = q ^ ((r >> 1) & 3);
        gl_lds16(Q + (size_t)r * 512 + kc * 128 + p * 32 + g * 8,
                 sQ + (size_t)(c * 256 + (t & ~63)) * 8);
      }
      __syncthreads();

#pragma unroll
      for (int kk = 0; kk < 4; ++kk) {
        const f16x8 aq = *(const f16x8*)(sQ + kk * 1024 + (wqm + lm) * 32 + sw);
        f16x8 bk[4];
#pragma unroll
        for (int j = 0; j < 4; ++j)
          bk[j] = *(const f16x8*)(sK + kk * 4096 + (wqn + j * 16 + lm) * 32 + sw);
#pragma unroll
        for (int j = 0; j < 4; ++j)
          sacc[j] = __builtin_amdgcn_mfma_f32_16x16x32_f16(aq, bk[j], sacc[j], 0, 0, 0);
      }
      __syncthreads();
    }

    // ---- mask + per-wave row max (C-layout: row=quad*4+r, col=lane&15) ----
#pragma unroll
    for (int r = 0; r < 4; ++r) {
      const int R = wqm + quad * 4 + r;
      const u16x4 aw = *(const u16x4*)(Ar + (size_t)R * 128 + nt * 8 + (wqn >> 4));
      float mx = -1e30f;
#pragma unroll
      for (int j = 0; j < 4; ++j) {
        float s = sacc[j][r];
        s = ((aw[j] >> lm) & 1u) ? s : -1e30f;
        sacc[j][r] = s;
        mx = fmaxf(mx, s);
      }
      mx = fmaxf(mx, __shfl_xor(mx, 1));
      mx = fmaxf(mx, __shfl_xor(mx, 2));
      mx = fmaxf(mx, __shfl_xor(mx, 4));
      mx = fmaxf(mx, __shfl_xor(mx, 8));
      if (lm == 0) rmA[wave & 1][R] = mx;
    }
    __syncthreads();  // B1

    // ---- exp + P~ to LDS + per-wave row sums ----
#pragma unroll
    for (int r = 0; r < 4; ++r) {
      const int R = wqm + quad * 4 + r;
      const float cm = fmaxf(rmA[0][R], rmA[1][R]);
      const float nm = fmaxf(m_sh[R], cm);
      float rs = 0.f;
#pragma unroll
      for (int j = 0; j < 4; ++j) {
        const float p = __expf(sacc[j][r] - nm);
        rs += p;
        sP[R * 136 + wqn + j * 16 + lm] = f2h(p);
      }
      rs += __shfl_xor(rs, 1);
      rs += __shfl_xor(rs, 2);
      rs += __shfl_xor(rs, 4);
      rs += __shfl_xor(rs, 8);
      if (lm == 0) rsA[wave & 1][R] = rs;
    }
    __syncthreads();  // B2

    // ---- state update ----
    if (t < 32) {
      const float cm = fmaxf(rmA[0][t], rmA[1][t]);
      const float mo = m_sh[t];
      const float nm = fmaxf(mo, cm);
      const float a  = __expf(mo - nm);
      l_sh[t]  = a * l_sh[t] + rsA[0][t] + rsA[1][t];
      m_sh[t]  = nm;
      al_sh[t] = a;
    }
    __syncthreads();  // B3

    // ---- O rescale + PV (V-frags direct from global hT; line-covered) ----
#pragma unroll
    for (int i = 0; i < 2; ++i)
#pragma unroll
      for (int r = 0; r < 4; ++r) {
        const float a = al_sh[i * 16 + quad * 4 + r];
#pragma unroll
        for (int j = 0; j < 8; ++j) o[i][j][r] *= a;
      }
#pragma unroll
    for (int kb = 0; kb < 4; ++kb) {
      f16x8 ap[2], bv[8];
#pragma unroll
      for (int i = 0; i < 2; ++i)
        ap[i] = *(const f16x8*)(sP + (i * 16 + lm) * 136 + kb * 32 + quad * 8);
#pragma unroll
      for (int j = 0; j < 8; ++j)
        bv[j] = *(const f16x8*)(V + (size_t)(wd + j * 16 + lm) * 2048 + n0 + kb * 32 + quad * 8);
#pragma unroll
      for (int i = 0; i < 2; ++i)
#pragma unroll
        for (int j = 0; j < 8; ++j)
          o[i][j] = __builtin_amdgcn_mfma_f32_16x16x32_f16(ap[i], bv[j], o[i][j], 0, 0, 0);
    }
  }

  // ---- epilogue: out = elu(O / l) ----
#pragma unroll
  for (int i = 0; i < 2; ++i)
#pragma unroll
    for (int r = 0; r < 4; ++r) {
      const int R = i * 16 + quad * 4 + r;
      const float inv = 1.f / l_sh[R];
#pragma unroll
      for (int j = 0; j < 8; ++j) {
        float v = o[i][j][r] * inv;
        v = v > 0.f ? v : expm1f(v);
        Co[(size_t)R * 512 + wd + j * 16 + lm] = v;
      }
    }
}

// ---------------------------------------------------------------------------
// adjacency -> bitmask: word i packs adj[i*16 .. i*16+16) (bit e = col e)
// ---------------------------------------------------------------------------
__global__ __launch_bounds__(256) void adj_pack(
    const int* __restrict__ adj, u16* __restrict__ outw, int nwords)
{
  const int i = blockIdx.x * 256 + threadIdx.x;
  if (i >= nwords) return;
  const int4* p = (const int4*)(adj + (size_t)i * 16);
  unsigned w = 0;
#pragma unroll
  for (int k = 0; k < 4; ++k) {
    int4 v = p[k];
    w |= (unsigned)(v.x != 0) << (k * 4 + 0);
    w |= (unsigned)(v.y != 0) << (k * 4 + 1);
    w |= (unsigned)(v.z != 0) << (k * 4 + 2);
    w |= (unsigned)(v.w != 0) << (k * 4 + 3);
  }
  outw[i] = (u16)w;
}

__global__ __launch_bounds__(256) void cvt_f32_f16(
    const float* __restrict__ in, u16* __restrict__ outp, int n4)
{
  const int i = blockIdx.x * 256 + threadIdx.x;
  if (i >= n4) return;
  float4 v = ((const float4*)in)[i];
  u16x4 o; o[0] = f2h(v.x); o[1] = f2h(v.y); o[2] = f2h(v.z); o[3] = f2h(v.w);
  ((u16x4*)outp)[i] = o;
}

__global__ __launch_bounds__(256) void transpose_cvt(
    const float* __restrict__ in, u16* __restrict__ outp, int R, int C)
{
  const int idx = blockIdx.x * 256 + threadIdx.x;
  const int i = idx / C, j = idx % C;
  outp[(size_t)j * R + i] = f2h(in[idx]);
}

// ---------------------------------------------------------------------------
extern "C" void kernel_launch(void* const* d_in, const int* in_sizes, int n_in,
                              void* d_out, int out_size, void* d_ws, size_t ws_size,
                              hipStream_t stream) {
  (void)in_sizes; (void)n_in; (void)out_size;
  const float* x    = (const float*)d_in[0];
  const int*   adj  = (const int*)d_in[1];
  const float* W    = (const float*)d_in[2];
  const float* bvec = (const float*)d_in[3];
  const float* attn = (const float*)d_in[4];
  float* out = (float*)d_out;

  constexpr int B = 8, N = 2048, D = 512;
  constexpr size_t MN = (size_t)B * N;  // 16384

  char* ws = (char*)d_ws;
  size_t off = 0;
  auto take = [&](size_t bytes) -> char* {
    char* p = ws + off;
    off += (bytes + 255) & ~(size_t)255;
    return p;
  };
  u16* xh   = (u16*)take(MN * D * 2);
  u16* Wh   = (u16*)take((size_t)D * D * 2);
  u16* attT = (u16*)take((size_t)D * D * 2);
  u16* h    = (u16*)take(MN * D * 2);
  u16* hT   = (u16*)take(MN * D * 2);
  u16* ha   = (u16*)take(MN * D * 2);
  u16* adjb = (u16*)take((size_t)B * N * (N / 16) * 2);  // 4 MB
  if (off > ws_size) return;

  // converts + adjacency pack
  cvt_f32_f16<<<dim3((unsigned)(MN * D / 4 / 256)), 256, 0, stream>>>(x, xh, (int)(MN * D / 4));
  cvt_f32_f16<<<dim3(D * D / 4 / 256), 256, 0, stream>>>(W, Wh, D * D / 4);
  transpose_cvt<<<dim3(D * D / 256), 256, 0, stream>>>(attn, attT, D, D);
  const int nwords = (int)(MN * (N / 16));
  adj_pack<<<dim3(nwords / 256), 256, 0, stream>>>(adj, adjb, nwords);

  // K1: h = xh . Wh^T + bias (also writes hT)
  gemm_bt<3><<<dim3(D / 128, MN / 128), 256, 0, stream>>>(
      xh, Wh, h, bvec, hT, D, D);
  // K2: ha = h . attT^T
  gemm_bt<0><<<dim3(D / 128, MN / 128), 256, 0, stream>>>(
      h, attT, ha, nullptr, nullptr, D, D);

  // fused S -> masked softmax -> PV -> elu
  flash_gat<<<dim3(512), 256, 0, stream>>>(ha, h, hT, adjb, out);
}